// Round 6
// baseline (743.815 us; speedup 1.0000x reference)
//
#include <hip/hip_runtime.h>

typedef __bf16 bf16_t;
typedef bf16_t bf16x8 __attribute__((ext_vector_type(8)));
typedef bf16_t bf16x4 __attribute__((ext_vector_type(4)));
typedef float f32x4 __attribute__((ext_vector_type(4)));
typedef unsigned int u32;

typedef __attribute__((address_space(1))) unsigned as1_u32;
typedef __attribute__((address_space(3))) unsigned as3_u32;

#define LOG2E 1.4426950408889634f
#define QSCALE (0.125f * LOG2E)       // fold softmax scale + log2(e) into Qp
#define MASK2 (-10000.0f * LOG2E)     // additive mask in exp2 domain

// async global->LDS, 16B per lane, LDS dest = wave-uniform base + lane*16
__device__ __forceinline__ void gload16(const void* g, void* l) {
  __builtin_amdgcn_global_load_lds((as1_u32*)(void*)g, (as3_u32*)l, 16, 0, 0);
}

// ---------------------------------------------------------------------------
// prep_all: one launch for (a) fp32->bf16 cvt of q,kv  [blocks 0..8191]
//                          (b) 6 weight transposes      [blocks 8192..11263]
//                          (c) mask build               [blocks 11264..11271]
struct TP { const float* s; bf16_t* d; int K; int N; };
struct PrepArgs {
  const float* q; const float* kv; bf16_t* qb; bf16_t* kvb;
  TP t[6];
  const unsigned char* mraw; float* maskf;
};
__global__ void prep_all(PrepArgs a) {
  __shared__ float tile[64][65];     // transpose staging; aliased by mask red
  const int bid = blockIdx.x, t = threadIdx.x;
  if (bid < 8192) {
    // ---- cvt: 8 elems/thread, 2048 elems/block, covers 2 x 8M
    long i = ((long)bid * 256 + t) * 8;
    const float* src; bf16_t* dst;
    if (i < 8388608) { src = a.q + i; dst = a.qb + i; }
    else { src = a.kv + (i - 8388608); dst = a.kvb + (i - 8388608); }
    const float4 x = *(const float4*)src;
    const float4 y = *(const float4*)(src + 4);
    bf16x8 o;
    o[0] = (bf16_t)x.x; o[1] = (bf16_t)x.y; o[2] = (bf16_t)x.z; o[3] = (bf16_t)x.w;
    o[4] = (bf16_t)y.x; o[5] = (bf16_t)y.y; o[6] = (bf16_t)y.z; o[7] = (bf16_t)y.w;
    *(bf16x8*)dst = o;
  } else if (bid < 11264) {
    // ---- transpose: W[K][N] fp32 -> WT[N][K] bf16
    int r2 = bid - 8192, z, tx, ty;
    if (r2 < 1024)      { z = r2 >> 8;  int r = r2 & 255;  tx = r & 15; ty = r >> 4; }
    else if (r2 < 2048) { z = 4;        int r = r2 - 1024; tx = r & 63; ty = r >> 6; }
    else                { z = 5;        int r = r2 - 2048; tx = r & 15; ty = r >> 4; }
    const TP w = a.t[z];
    const int n0 = tx * 64, k0 = ty * 64;
#pragma unroll
    for (int i = 0; i < 16; i++) {
      int e = i * 256 + t; int r = e >> 6, c = e & 63;
      tile[r][c] = w.s[(size_t)(k0 + r) * w.N + n0 + c];
    }
    __syncthreads();
#pragma unroll
    for (int i = 0; i < 16; i++) {
      int e = i * 256 + t; int r = e >> 6, c = e & 63;
      w.d[(size_t)(n0 + r) * w.K + k0 + c] = (bf16_t)tile[c][r];
    }
  } else {
    // ---- mask: detect bool-bytes vs int32; additive exp2-domain mask with
    // the "all-pad row -> unmask last key" fix
    int* sred = (int*)&tile[0][0];
    const int b = bid - 11264;
    int f = 0;
    for (int i = t; i < 2048; i += 256) {
      u32 v = ((const u32*)a.mraw)[i];
      if (v & 0xFFFFFF00u) f = 1;
    }
    sred[t] = f; __syncthreads();
    for (int s = 128; s; s >>= 1) { if (t < s) sred[t] |= sred[t + s]; __syncthreads(); }
    const int isByte = sred[0];
    __syncthreads();
    int vals[4]; int allpad = 1;
#pragma unroll
    for (int i = 0; i < 4; i++) {
      int k = t * 4 + i;
      int mv = isByte ? (int)a.mraw[b * 1024 + k] : ((const int*)a.mraw)[b * 1024 + k];
      vals[i] = (mv != 0);
      allpad &= vals[i];
    }
    sred[t] = allpad; __syncthreads();
    for (int s = 128; s; s >>= 1) { if (t < s) sred[t] &= sred[t + s]; __syncthreads(); }
    const int ap = sred[0];
#pragma unroll
    for (int i = 0; i < 4; i++) {
      int k = t * 4 + i;
      int m = vals[i];
      if (ap && k == 1023) m = 0;
      a.maskf[b * 1024 + k] = m ? MASK2 : 0.0f;
    }
  }
}

// ---------------------------------------------------------------------------
// Shared MFMA GEMM body: C[M][N] = (A @ BT^T + bias)*scale (+relu), bf16 io,
// fp32 accum. 128x128 tile, BK=32, global_load_lds staging (m97 structure).
__device__ __forceinline__ void gemm_body(
    const bf16_t* __restrict__ A, const bf16_t* __restrict__ BT,
    const float* __restrict__ bias, bf16_t* __restrict__ C,
    int N, int K, int relu, int bias_mode, float scale,
    long bm, long bn, bf16_t* As, bf16_t* Bs, int tid) {
  const int wave = tid >> 6, lane = tid & 63;
  const int quad = lane >> 4, l15 = lane & 15;
  const int wm = (wave >> 1) * 64, wn = (wave & 1) * 64;

  f32x4 acc[4][4];
#pragma unroll
  for (int i = 0; i < 4; i++)
#pragma unroll
    for (int j = 0; j < 4; j++) acc[i][j] = (f32x4){0.f, 0.f, 0.f, 0.f};

  const bf16_t* ag = A + (bm + wave * 32 + (lane >> 2)) * (long)K + (lane & 3) * 8;
  const bf16_t* bg = BT + (bn + wave * 32 + (lane >> 2)) * (long)K + (lane & 3) * 8;
  bf16_t* as_dst = &As[wave * 1024];
  bf16_t* bs_dst = &Bs[wave * 1024];

  for (int k0 = 0; k0 < K; k0 += 32) {
    gload16(ag + k0, as_dst);
    gload16(ag + k0 + (long)16 * K, as_dst + 512);
    gload16(bg + k0, bs_dst);
    gload16(bg + k0 + (long)16 * K, bs_dst + 512);
    __syncthreads();

    bf16x8 af[4], bf[4];
#pragma unroll
    for (int i = 0; i < 4; i++)
      af[i] = *(const bf16x8*)&As[(wm + i * 16 + l15) * 32 + quad * 8];
#pragma unroll
    for (int i = 0; i < 4; i++)
      bf[i] = *(const bf16x8*)&Bs[(wn + i * 16 + l15) * 32 + quad * 8];
#pragma unroll
    for (int mi = 0; mi < 4; mi++)
#pragma unroll
      for (int ni = 0; ni < 4; ni++)
        acc[mi][ni] = __builtin_amdgcn_mfma_f32_16x16x32_bf16(af[mi], bf[ni], acc[mi][ni], 0, 0, 0);
    __syncthreads();
  }

#pragma unroll
  for (int mi = 0; mi < 4; mi++) {
#pragma unroll
    for (int ni = 0; ni < 4; ni++) {
      const long col = bn + wn + ni * 16 + l15;
      const float bc = bias_mode ? 0.f : bias[col];
#pragma unroll
      for (int r = 0; r < 4; r++) {
        const long row = bm + wm + mi * 16 + quad * 4 + r;
        const float bb = bias_mode ? bias[row] : bc;
        float v = (acc[mi][ni][r] + bb) * scale;
        if (relu) v = v > 0.f ? v : 0.f;
        C[row * N + col] = (bf16_t)v;
      }
    }
  }
}

// generic launcher: grid (N/128, M/128)
__global__ __launch_bounds__(256)
void gemm_bt(const bf16_t* __restrict__ A, const bf16_t* __restrict__ BT,
             const float* __restrict__ bias, bf16_t* __restrict__ C,
             int N, int K, int relu, int bias_mode, float scale) {
  __shared__ __align__(16) bf16_t As[128 * 32];
  __shared__ __align__(16) bf16_t Bs[128 * 32];
  gemm_body(A, BT, bias, C, N, K, relu, bias_mode, scale,
            (long)blockIdx.y * 128, (long)blockIdx.x * 128, As, Bs, threadIdx.x);
}

// fused QKV projections: grid (8, 64, 3).
// z=0: Qp = (qb@Wq+bq)*QSCALE ; z=1: Kp = kvb@Wk+bk ;
// z=2: VT = (kvb@Wv+bv)^T  via swapped operands (M=1024, N=8192, bias on rows)
struct QKVArgs {
  const bf16_t *qb, *kvb, *WqT, *WkT, *WvT;
  const float *bq, *bk, *bv;
  bf16_t *Qp, *Kp, *VT;
};
__global__ __launch_bounds__(256)
void qkv_proj(QKVArgs a) {
  __shared__ __align__(16) bf16_t As[128 * 32];
  __shared__ __align__(16) bf16_t Bs[128 * 32];
  const int z = blockIdx.z;
  if (z == 2) {
    gemm_body(a.WvT, a.kvb, a.bv, a.VT, 8192, 1024, 0, 1, 1.f,
              (long)blockIdx.x * 128, (long)blockIdx.y * 128, As, Bs, threadIdx.x);
  } else if (z == 1) {
    gemm_body(a.kvb, a.WkT, a.bk, a.Kp, 1024, 1024, 0, 0, 1.f,
              (long)blockIdx.y * 128, (long)blockIdx.x * 128, As, Bs, threadIdx.x);
  } else {
    gemm_body(a.qb, a.WqT, a.bq, a.Qp, 1024, 1024, 0, 0, QSCALE,
              (long)blockIdx.y * 128, (long)blockIdx.x * 128, As, Bs, threadIdx.x);
  }
}

// ---------------------------------------------------------------------------
// Flash attention (round 6): 64-query blocks, 16 queries/wave, 8 blocks/CU.
// 1D grid 2048, XCD-affine: id%8 = b (batch's K/V slice L2-resident per XCD).
// S^T = K.Q^T (per-lane softmax stats), direct-from-L2 K/V frags, barrier-free
// kt loop, P roundtrip through per-wave LDS, O^T accumulation.
__global__ __launch_bounds__(256, 8)
void attn(const bf16_t* __restrict__ Q, const bf16_t* __restrict__ Kp,
          const bf16_t* __restrict__ Vt, const float* __restrict__ maskf,
          bf16_t* __restrict__ AO) {
  __shared__ __align__(16) bf16_t QsPs[64 * 64];    // Q stage, then P (union)
  __shared__ float msk[1024];

  const int tid = threadIdx.x;
  const int wave = tid >> 6, lane = tid & 63;
  const int quad = lane >> 4, l15 = lane & 15;
  const int id = blockIdx.x;
  const int b = id & 7;
  const int h = (id >> 3) & 15;
  const int q0 = (id >> 7) * 64;

  const long base_q = ((long)b * 1024 + q0) * 1024 + h * 64;

  // stage additive mask (exp2 domain) for this batch
  *(float4*)&msk[tid * 4] = *(const float4*)(maskf + (long)b * 1024 + tid * 4);

  // stage Q tile 64x64, XOR-swizzled 16B blocks by (row&7)
  {
    int e = tid * 2;                       // 512 chunks, 2/thread
#pragma unroll
    for (int i = 0; i < 2; i++) {
      int r = (e + i) >> 3, blk = (e + i) & 7;
      const int4 v = *(const int4*)(Q + base_q + (long)r * 1024 + blk * 8);
      *(int4*)&QsPs[r * 64 + ((blk ^ (r & 7)) * 8)] = v;
    }
  }
  __syncthreads();

  // hoist Q B-frags: wave owns queries wave*16 + l15
  bf16x8 aq[2];
#pragma unroll
  for (int ks = 0; ks < 2; ks++) {
    int row = wave * 16 + l15;
    aq[ks] = *(const bf16x8*)&QsPs[row * 64 + (((ks * 4 + quad) ^ (row & 7)) * 8)];
  }
  __syncthreads();          // Qs dead -> per-wave P buffers
  bf16_t* Pw = &QsPs[wave * 16 * 64];

  const bf16_t* kb = Kp + ((long)b * 1024 + l15) * 1024 + h * 64 + quad * 8;
  const bf16_t* vb = Vt + ((long)h * 64 + l15) * 8192 + (long)b * 1024 + quad * 8;

  float m_i = -1e30f, l_i = 0.f;
  f32x4 o[4];
#pragma unroll
  for (int mt = 0; mt < 4; mt++) o[mt] = (f32x4){0.f, 0.f, 0.f, 0.f};

  for (int kt = 0; kt < 16; kt++) {
    const int k0 = kt * 64;

    // S^T: A = K rows (key = k0+nt*16+l15), B = Q
    f32x4 sc[4];
#pragma unroll
    for (int nt = 0; nt < 4; nt++) {
      f32x4 s = (f32x4){0.f, 0.f, 0.f, 0.f};
#pragma unroll
      for (int ks = 0; ks < 2; ks++) {
        const bf16x8 bk = *(const bf16x8*)(kb + (long)(k0 + nt * 16) * 1024 + ks * 32);
        s = __builtin_amdgcn_mfma_f32_16x16x32_bf16(bk, aq[ks], s, 0, 0, 0);
      }
      sc[nt] = s;
    }

    // additive mask (key = k0 + nt*16 + quad*4 + r)
#pragma unroll
    for (int nt = 0; nt < 4; nt++)
      sc[nt] += *(const f32x4*)&msk[k0 + nt * 16 + quad * 4];

    // online softmax: per-lane stats (query = l15), cross-quad shfl only
    f32x4 m4 = sc[0];
#pragma unroll
    for (int nt = 1; nt < 4; nt++) {
      m4[0] = fmaxf(m4[0], sc[nt][0]); m4[1] = fmaxf(m4[1], sc[nt][1]);
      m4[2] = fmaxf(m4[2], sc[nt][2]); m4[3] = fmaxf(m4[3], sc[nt][3]);
    }
    float mx = fmaxf(fmaxf(m4[0], m4[1]), fmaxf(m4[2], m4[3]));
    mx = fmaxf(mx, __shfl_xor(mx, 16));
    mx = fmaxf(mx, __shfl_xor(mx, 32));
    const float mnew = fmaxf(m_i, mx);
    const float alpha = exp2f(m_i - mnew);
    m_i = mnew;
    float ps = 0.f;
#pragma unroll
    for (int nt = 0; nt < 4; nt++)
#pragma unroll
      for (int r = 0; r < 4; r++) {
        float p = exp2f(sc[nt][r] - mnew);
        sc[nt][r] = p;
        ps += p;
      }
    l_i = l_i * alpha + ps;
#pragma unroll
    for (int mt = 0; mt < 4; mt++) o[mt] *= alpha;

    // P row (query l15): 4 keys per b64, swizzled; same-wave readback
#pragma unroll
    for (int nt = 0; nt < 4; nt++) {
      bf16x4 pp;
      pp[0] = (bf16_t)sc[nt][0]; pp[1] = (bf16_t)sc[nt][1];
      pp[2] = (bf16_t)sc[nt][2]; pp[3] = (bf16_t)sc[nt][3];
      const int kblk = nt * 2 + (quad >> 1);
      *(bf16x4*)&Pw[l15 * 64 + ((kblk ^ (l15 & 7)) * 8) + (quad & 1) * 4] = pp;
    }

    bf16x8 bp[2];
#pragma unroll
    for (int ks = 0; ks < 2; ks++)
      bp[ks] = *(const bf16x8*)&Pw[l15 * 64 + (((ks * 4 + quad) ^ (l15 & 7)) * 8)];

    // O^T += V^T . P^T : A = V rows (hd = mt*16+l15) direct from L2
#pragma unroll
    for (int mt = 0; mt < 4; mt++)
#pragma unroll
      for (int ks = 0; ks < 2; ks++) {
        const bf16x8 av = *(const bf16x8*)(vb + (long)(mt * 16) * 8192 + k0 + ks * 32);
        o[mt] = __builtin_amdgcn_mfma_f32_16x16x32_bf16(av, bp[ks], o[mt], 0, 0, 0);
      }
  }

  // epilogue: O^T col=query(l15), row=hd(mt*16+quad*4+r)
  float lt = l_i;
  lt += __shfl_xor(lt, 16);
  lt += __shfl_xor(lt, 32);
  const float rinv = 1.0f / lt;
  const long tok = (long)b * 1024 + q0 + wave * 16 + l15;
#pragma unroll
  for (int mt = 0; mt < 4; mt++) {
    bf16x4 ov;
    ov[0] = (bf16_t)(o[mt][0] * rinv); ov[1] = (bf16_t)(o[mt][1] * rinv);
    ov[2] = (bf16_t)(o[mt][2] * rinv); ov[3] = (bf16_t)(o[mt][3] * rinv);
    *(bf16x4*)&AO[tok * 1024 + h * 64 + mt * 16 + quad * 4] = ov;
  }
}

// ---------------------------------------------------------------------------
// LN1: out_bf16[row] = LN(q_f32[row] + xb_bf16[row]) * g + bt. one block/row.
__global__ __launch_bounds__(256)
void ln_res1(const float* __restrict__ xa, const bf16_t* __restrict__ xb,
             const float* __restrict__ g, const float* __restrict__ bt,
             bf16_t* __restrict__ out) {
  __shared__ float sw[8];
  const int t = threadIdx.x, w = t >> 6;
  const long row = blockIdx.x;
  const float4 a = *(const float4*)(xa + row * 1024 + t * 4);
  const bf16x4 bq = *(const bf16x4*)(xb + row * 1024 + t * 4);
  float v[4] = {a.x + (float)bq[0], a.y + (float)bq[1],
                a.z + (float)bq[2], a.w + (float)bq[3]};
  float s = v[0] + v[1] + v[2] + v[3];
  float s2 = v[0]*v[0] + v[1]*v[1] + v[2]*v[2] + v[3]*v[3];
#pragma unroll
  for (int off = 1; off < 64; off <<= 1) {
    s += __shfl_xor(s, off); s2 += __shfl_xor(s2, off);
  }
  if ((t & 63) == 0) { sw[w] = s; sw[4 + w] = s2; }
  __syncthreads();
  s = sw[0] + sw[1] + sw[2] + sw[3];
  s2 = sw[4] + sw[5] + sw[6] + sw[7];
  const float mean = s * (1.f / 1024.f);
  const float var = s2 * (1.f / 1024.f) - mean * mean;
  const float rstd = rsqrtf(var + 1e-5f);
  bf16x4 o;
#pragma unroll
  for (int i = 0; i < 4; i++) {
    const int c = t * 4 + i;
    o[i] = (bf16_t)((v[i] - mean) * rstd * g[c] + bt[c]);
  }
  *(bf16x4*)(out + row * 1024 + t * 4) = o;
}

// LN2: out_f32[row] = LN(xa_bf16[row] + xb_bf16[row]) * g + bt. one block/row.
__global__ __launch_bounds__(256)
void ln_res2(const bf16_t* __restrict__ xa, const bf16_t* __restrict__ xb,
             const float* __restrict__ g, const float* __restrict__ bt,
             float* __restrict__ out) {
  __shared__ float sw[8];
  const int t = threadIdx.x, w = t >> 6;
  const long row = blockIdx.x;
  const bf16x4 aq = *(const bf16x4*)(xa + row * 1024 + t * 4);
  const bf16x4 bq = *(const bf16x4*)(xb + row * 1024 + t * 4);
  float v[4];
#pragma unroll
  for (int i = 0; i < 4; i++) v[i] = (float)aq[i] + (float)bq[i];
  float s = v[0] + v[1] + v[2] + v[3];
  float s2 = v[0]*v[0] + v[1]*v[1] + v[2]*v[2] + v[3]*v[3];
#pragma unroll
  for (int off = 1; off < 64; off <<= 1) {
    s += __shfl_xor(s, off); s2 += __shfl_xor(s2, off);
  }
  if ((t & 63) == 0) { sw[w] = s; sw[4 + w] = s2; }
  __syncthreads();
  s = sw[0] + sw[1] + sw[2] + sw[3];
  s2 = sw[4] + sw[5] + sw[6] + sw[7];
  const float mean = s * (1.f / 1024.f);
  const float var = s2 * (1.f / 1024.f) - mean * mean;
  const float rstd = rsqrtf(var + 1e-5f);
  float4 o;
  o.x = (v[0] - mean) * rstd * g[t*4+0] + bt[t*4+0];
  o.y = (v[1] - mean) * rstd * g[t*4+1] + bt[t*4+1];
  o.z = (v[2] - mean) * rstd * g[t*4+2] + bt[t*4+2];
  o.w = (v[3] - mean) * rstd * g[t*4+3] + bt[t*4+3];
  *(float4*)(out + row * 1024 + t * 4) = o;
}

// ---------------------------------------------------------------------------
extern "C" void kernel_launch(void* const* d_in, const int* in_sizes, int n_in,
                              void* d_out, int out_size, void* d_ws, size_t ws_size,
                              hipStream_t stream) {
  (void)in_sizes; (void)n_in; (void)out_size; (void)ws_size;
  const float* q   = (const float*)d_in[0];
  const float* kv  = (const float*)d_in[1];
  const unsigned char* mraw = (const unsigned char*)d_in[2];
  const float* Wq = (const float*)d_in[3];
  const float* bq = (const float*)d_in[4];
  const float* Wk = (const float*)d_in[5];
  const float* bk = (const float*)d_in[6];
  const float* Wv = (const float*)d_in[7];
  const float* bv = (const float*)d_in[8];
  const float* Wo = (const float*)d_in[9];
  const float* bo = (const float*)d_in[10];
  const float* g1 = (const float*)d_in[11];
  const float* be1 = (const float*)d_in[12];
  const float* W1 = (const float*)d_in[13];
  const float* b1 = (const float*)d_in[14];
  const float* W2 = (const float*)d_in[15];
  const float* b2 = (const float*)d_in[16];
  const float* g2 = (const float*)d_in[17];
  const float* be2 = (const float*)d_in[18];
  float* out = (float*)d_out;

  char* ws = (char*)d_ws;
  size_t off = 0;
  auto alloc = [&](size_t bytes) -> char* {
    char* p = ws + off; off += (bytes + 255) & ~(size_t)255; return p;
  };
  const size_t MB16 = (size_t)8192 * 1024 * 2;   // one [8192,1024] bf16 buffer
  float*  maskf = (float*)alloc(8192 * 4);
  bf16_t* WqT = (bf16_t*)alloc((size_t)1024 * 1024 * 2);
  bf16_t* WkT = (bf16_t*)alloc((size_t)1024 * 1024 * 2);
  bf16_t* WvT = (bf16_t*)alloc((size_t)1024 * 1024 * 2);
  bf16_t* WoT = (bf16_t*)alloc((size_t)1024 * 1024 * 2);
  bf16_t* W1T = (bf16_t*)alloc((size_t)1024 * 4096 * 2);
  bf16_t* W2T = (bf16_t*)alloc((size_t)4096 * 1024 * 2);
  bf16_t* Qp = (bf16_t*)alloc(MB16);
  bf16_t* Kp = (bf16_t*)alloc(MB16);
  bf16_t* VT = (bf16_t*)alloc(MB16);   // [1024 (h*64+hd)][8192 (b*1024+tok)]
  bf16_t* AO = (bf16_t*)alloc(MB16);
  bf16_t* X1 = (bf16_t*)alloc(MB16);
  bf16_t* TL = (bf16_t*)alloc(MB16);
  // aliases (lifetimes verified):
  bf16_t* qb  = X1;   // bf16 q; dead before ln_res1 writes X1
  bf16_t* kvb = TL;   // bf16 kv; dead after K/V projections
  bf16_t* HF  = Qp;   // [8192,4096] spans Qp..AO; all dead by FFN1
  bf16_t* OP  = Kp;   // o-proj out; Kp dead after attention
  bf16_t* F2  = WqT;  // [8192,1024] spans WqT..W1T (16MB); W2T untouched

  PrepArgs pa;
  pa.q = q; pa.kv = kv; pa.qb = qb; pa.kvb = kvb;
  pa.t[0] = {Wq, WqT, 1024, 1024}; pa.t[1] = {Wk, WkT, 1024, 1024};
  pa.t[2] = {Wv, WvT, 1024, 1024}; pa.t[3] = {Wo, WoT, 1024, 1024};
  pa.t[4] = {W1, W1T, 1024, 4096}; pa.t[5] = {W2, W2T, 4096, 1024};
  pa.mraw = mraw; pa.maskf = maskf;
  prep_all<<<11272, 256, 0, stream>>>(pa);

  QKVArgs qa = {qb, kvb, WqT, WkT, WvT, bq, bk, bv, Qp, Kp, VT};
  qkv_proj<<<dim3(8, 64, 3), 256, 0, stream>>>(qa);

  attn<<<2048, 256, 0, stream>>>(Qp, Kp, VT, maskf, AO);

  gemm_bt<<<dim3(8, 64), 256, 0, stream>>>(AO, WoT, bo, OP, 1024, 1024, 0, 0, 1.f);
  ln_res1<<<8192, 256, 0, stream>>>(q, OP, g1, be1, X1);

  gemm_bt<<<dim3(32, 64), 256, 0, stream>>>(X1, W1T, b1, HF, 4096, 1024, 1, 0, 1.f);
  gemm_bt<<<dim3(8, 64), 256, 0, stream>>>(HF, W2T, b2, F2, 1024, 4096, 0, 0, 1.f);
  ln_res2<<<8192, 256, 0, stream>>>(X1, F2, g2, be2, out);
}